// Round 22
// baseline (227.795 us; speedup 1.0000x reference)
//
#include <hip/hip_runtime.h>
#include <hip/hip_bf16.h>
#include <math.h>

#define H_DIM 1024
#define SEQ   2048
#define BATCH 2
#define NHEAD 16
#define DKV   64
#define ROWS  (BATCH*SEQ)   // 4096
#define QSCALE 0.18033688f  // 0.125 * log2(e): scores land in log2 domain

typedef __attribute__((ext_vector_type(8))) short short8;
typedef __attribute__((ext_vector_type(4))) float f32x4;

static __device__ __forceinline__ unsigned short f32_bf16(float f) {
    unsigned int u = __builtin_bit_cast(unsigned int, f);
    u += 0x7FFF + ((u >> 16) & 1);          // RNE
    return (unsigned short)(u >> 16);
}
static __device__ __forceinline__ float bf16_f32(unsigned short h) {
    return __builtin_bit_cast(float, (unsigned int)h << 16);
}

// A&S 7.1.26 rational-poly erf, |err| < 1.5e-7
static __device__ __forceinline__ float fast_erf(float x) {
    float ax = fabsf(x);
    float t = 1.0f / fmaf(0.3275911f, ax, 1.0f);
    float p = t * fmaf(t, fmaf(t, fmaf(t, fmaf(t, 1.061405429f, -1.453152027f),
                                       1.421413741f), -0.284496736f), 0.254829592f);
    float y = fmaf(-p, __expf(-ax * ax), 1.0f);
    return copysignf(y, x);
}

static __device__ __forceinline__ void gload16(const unsigned short* g, unsigned short* l) {
    __builtin_amdgcn_global_load_lds(
        (const __attribute__((address_space(1))) void*)g,
        (__attribute__((address_space(3))) void*)l,
        16, 0, 0);
}

// ---------------- fused fp32 [K][N] -> bf16 [N][K] transpose for ALL 4 weights ----------------
__global__ __launch_bounds__(256) void transpose_all(const float* __restrict__ Wqkv,
                                                     const float* __restrict__ Wo,
                                                     const float* __restrict__ Wfc,
                                                     const float* __restrict__ Wproj,
                                                     unsigned short* __restrict__ WqT,
                                                     unsigned short* __restrict__ WoT,
                                                     unsigned short* __restrict__ WfcT,
                                                     unsigned short* __restrict__ WpT) {
    int t = blockIdx.x;
    const float* in; unsigned short* out; int K, N;
    if (t < 3072)      { in = Wqkv;  out = WqT;  K = 1024; N = 3072; }
    else if (t < 4096) { in = Wo;    out = WoT;  K = 1024; N = 1024; t -= 3072; }
    else if (t < 8192) { in = Wfc;   out = WfcT; K = 1024; N = 4096; t -= 4096; }
    else               { in = Wproj; out = WpT;  K = 4096; N = 1024; t -= 8192; }
    int ntx = N >> 5;
    int n0 = (t % ntx) * 32, k0 = (t / ntx) * 32;

    __shared__ float tile[32][33];
    int tx = threadIdx.x & 31, ty = threadIdx.x >> 5;   // 32 x 8
    #pragma unroll
    for (int i = 0; i < 4; ++i)
        tile[ty + i * 8][tx] = in[(size_t)(k0 + ty + i * 8) * N + n0 + tx];
    __syncthreads();
    #pragma unroll
    for (int i = 0; i < 4; ++i)
        out[(size_t)(n0 + ty + i * 8) * K + k0 + tx] = f32_bf16(tile[tx][ty + i * 8]);
}

// ---------------- LayerNorm (fp32 or bf16 in -> bf16 out) ----------------
template<int BF16IN>
__global__ __launch_bounds__(256) void ln_any(const void* __restrict__ xin,
                                              const float* __restrict__ w,
                                              const float* __restrict__ bb,
                                              unsigned short* __restrict__ out) {
    int row = blockIdx.x;
    int tid = threadIdx.x;
    float4 v;
    if (BF16IN) {
        ushort4 u = ((const ushort4*)((const unsigned short*)xin + (size_t)row * H_DIM))[tid];
        v.x = bf16_f32(u.x); v.y = bf16_f32(u.y); v.z = bf16_f32(u.z); v.w = bf16_f32(u.w);
    } else {
        v = ((const float4*)((const float*)xin + (size_t)row * H_DIM))[tid];
    }
    float s  = v.x + v.y + v.z + v.w;
    float s2 = v.x*v.x + v.y*v.y + v.z*v.z + v.w*v.w;
    #pragma unroll
    for (int off = 1; off < 64; off <<= 1) {
        s  += __shfl_xor(s,  off, 64);
        s2 += __shfl_xor(s2, off, 64);
    }
    __shared__ float red[8];
    int wv = tid >> 6;
    if ((tid & 63) == 0) { red[wv] = s; red[4 + wv] = s2; }
    __syncthreads();
    s  = red[0] + red[1] + red[2] + red[3];
    s2 = red[4] + red[5] + red[6] + red[7];
    float mu = s * (1.0f / H_DIM);
    float rs = rsqrtf(s2 * (1.0f / H_DIM) - mu * mu + 1e-5f);
    float4 wv4 = ((const float4*)w)[tid];
    float4 bv4 = ((const float4*)bb)[tid];
    ushort4 o;
    o.x = f32_bf16((v.x - mu) * rs * wv4.x + bv4.x);
    o.y = f32_bf16((v.y - mu) * rs * wv4.y + bv4.y);
    o.z = f32_bf16((v.z - mu) * rs * wv4.z + bv4.z);
    o.w = f32_bf16((v.w - mu) * rs * wv4.w + bv4.w);
    ((ushort4*)(out + (size_t)row * H_DIM))[tid] = o;
}

// ======== epilogue helper ========
template<int EPI>
static __device__ __forceinline__ void epi_store(f32x4 a, int row0, int col, int N,
                                                 const float* __restrict__ bias,
                                                 const float* __restrict__ resid,
                                                 float* __restrict__ outF,
                                                 unsigned short* __restrict__ outH,
                                                 unsigned short* __restrict__ outH2) {
    float bv = bias[col];
    if (EPI == 4 && col >= 2048) {
        int bb = row0 >> 11, ss = row0 & 2047;
        int hd = col - 2048;
        ushort4 u;
        u.x = f32_bf16(a[0] + bv);
        u.y = f32_bf16(a[1] + bv);
        u.z = f32_bf16(a[2] + bv);
        u.w = f32_bf16(a[3] + bv);
        *(ushort4*)&outH2[((size_t)bb * 1024 + hd) * SEQ + ss] = u;
    } else {
        #pragma unroll
        for (int j = 0; j < 4; ++j) {
            int row = row0 + j;
            size_t idx = (size_t)row * N + col;
            float c = a[j] + bv;
            if (EPI == 0) {
                outF[idx] = c;
            } else if (EPI == 1) {
                outF[idx] = resid[idx] + c;
            } else if (EPI == 2) {
                float g = 0.5f * c * (1.0f + fast_erf(c * 0.70710678118f));
                outH[idx] = f32_bf16(g);
            } else if (EPI == 3) {
                outH[idx] = f32_bf16(c);
            } else if (EPI == 5) {
                outH[idx] = f32_bf16(resid[idx] + c);
            } else if (EPI == 6) {
                outF[idx] = bf16_f32(outH2[idx]) + c;
            } else {
                float c2 = (col < 1024) ? c * QSCALE : c;
                outH[(size_t)row * 2048 + col] = f32_bf16(c2);
            }
        }
    }
}

// ---------------- bf16 MFMA GEMM, 128 x (NI*32) tile, BK=64, single-buffer,
//                  8 waves, wave-tile 64 x (NI*8); 2D XCD chunking (round-17 proven) ------
template<int EPI, int NI>
__global__ __launch_bounds__(512) void gemmT(const unsigned short* __restrict__ A,
                                             const unsigned short* __restrict__ Bt,
                                             const float* __restrict__ bias,
                                             const float* __restrict__ resid,
                                             float* __restrict__ outF,
                                             unsigned short* __restrict__ outH,
                                             unsigned short* __restrict__ outH2,
                                             int cm, int cn, int ncc, int N, int K) {
    constexpr int BN = NI * 32;
    constexpr int WN = BN / 4;
    constexpr int NT = WN / 16;
    __shared__ __attribute__((aligned(16))) unsigned short As[128][64];
    __shared__ __attribute__((aligned(16))) unsigned short Bs[BN][64];
    int tid = threadIdx.x;
    int w = tid >> 6, l = tid & 63;
    int l15 = l & 15, lg = l >> 4;
    int wm = w & 1, wn = w >> 1;

    int c = blockIdx.x & 7, lwg = blockIdx.x >> 3;
    int lm = lwg / cn, ln = lwg - lm * cn;
    int ccr = c / ncc;
    int bm = ccr * cm + lm;
    int bn = (c - ccr * ncc) * cn + ln;
    int m0 = bm * 128, n0 = bn * BN;

    f32x4 acc[4][NT] = {};

    const unsigned short* aptr[2];
    unsigned short* lA[2];
    #pragma unroll
    for (int j = 0; j < 2; ++j) {
        int slot = j * 512 + tid;
        int row = slot >> 3;
        int lchunk = (slot & 7) ^ (row & 7);
        aptr[j] = A + (size_t)(m0 + row) * K + lchunk * 8;
        lA[j] = &As[0][0] + (size_t)slot * 8 - l * 8;
    }
    const unsigned short* bptr[NI / 2];
    unsigned short* lB[NI / 2];
    #pragma unroll
    for (int j = 0; j < NI / 2; ++j) {
        int slot = j * 512 + tid;
        int row = slot >> 3;
        int lchunk = (slot & 7) ^ (row & 7);
        bptr[j] = Bt + (size_t)(n0 + row) * K + lchunk * 8;
        lB[j] = &Bs[0][0] + (size_t)slot * 8 - l * 8;
    }
    int swz[2];
    swz[0] = ((0 + lg) ^ (l15 & 7)) * 8;
    swz[1] = ((4 + lg) ^ (l15 & 7)) * 8;
    const unsigned short* pA = &As[wm * 64 + l15][0];
    const unsigned short* pB = &Bs[wn * WN + l15][0];

    for (int k0 = 0; k0 < K; k0 += 64) {
        __syncthreads();
        #pragma unroll
        for (int j = 0; j < 2; ++j) gload16(aptr[j] + k0, lA[j]);
        #pragma unroll
        for (int j = 0; j < NI / 2; ++j) gload16(bptr[j] + k0, lB[j]);
        __syncthreads();

        #pragma unroll
        for (int ks = 0; ks < 2; ++ks) {
            short8 af[4], bf[NT];
            #pragma unroll
            for (int mi = 0; mi < 4; ++mi)
                af[mi] = *(const short8*)(pA + mi * 16 * 64 + swz[ks]);
            #pragma unroll
            for (int ni = 0; ni < NT; ++ni)
                bf[ni] = *(const short8*)(pB + ni * 16 * 64 + swz[ks]);
            #pragma unroll
            for (int mi = 0; mi < 4; ++mi)
                #pragma unroll
                for (int ni = 0; ni < NT; ++ni)
                    acc[mi][ni] = __builtin_amdgcn_mfma_f32_16x16x32_bf16(af[mi], bf[ni], acc[mi][ni], 0, 0, 0);
        }
    }

    #pragma unroll
    for (int mi = 0; mi < 4; ++mi)
        #pragma unroll
        for (int ni = 0; ni < NT; ++ni)
            epi_store<EPI>(acc[mi][ni], m0 + wm * 64 + mi * 16 + lg * 4,
                           n0 + wn * WN + ni * 16 + l15, N, bias, resid, outF, outH, outH2);
}

// ---------------- causal flash attention: QBLK=64, 4 waves, UNPAIRED grid 1024
//                  (3 blocks/CU co-residency; long-first within XCD chunks) ----------------
__global__ __launch_bounds__(256) void attn_mfma(const unsigned short* __restrict__ qk,
                                                 const unsigned short* __restrict__ vT,
                                                 unsigned short* __restrict__ out) {
    int bid = blockIdx.x;
    int swz = (bid & 7) * 128 + (bid >> 3);   // 1024 % 8 == 0 -> bijective
    int b  = swz >> 9;
    int h  = (swz >> 5) & 15;
    int qt = 31 - (swz & 31);                 // long blocks first
    int tid = threadIdx.x;
    int w = tid >> 6, l = tid & 63;
    int l15 = l & 15, lg = l >> 4;

    __shared__ __attribute__((aligned(16))) unsigned short Ks[2][64][64];
    __shared__ __attribute__((aligned(16))) unsigned short Vt[2][64][64];
    __shared__ __attribute__((aligned(16))) unsigned short Ps[4][16][72];

    short8 vf5;
    #pragma unroll
    for (int i = 0; i < 8; ++i) vf5[i] = (l15 == 0) ? (short)0x3F80 : (short)0;

    int sr = tid >> 2;                        // 0..63
    int c0 = (tid & 3) * 2, c1 = c0 + 1;
    int sp0 = ((c0 ^ (sr & 7)) * 8);
    int sp1 = ((c1 ^ (sr & 7)) * 8);
    const unsigned short* kb0 = qk + (size_t)(b * SEQ + sr) * 2048 + 1024 + h * DKV + c0 * 8;
    const unsigned short* kb1 = kb0 + 8;
    const unsigned short* vb0 = vT + ((size_t)(b * NHEAD + h) * DKV + sr) * SEQ + c0 * 8;
    const unsigned short* vb1 = vb0 + 8;

    int rk0 = ((0 + lg) ^ (l15 & 7)) * 8;
    int rk1 = ((4 + lg) ^ (l15 & 7)) * 8;

    int qrow = qt * 64 + w * 16 + l15;
    const unsigned short* qp = qk + (size_t)(b * SEQ + qrow) * 2048 + h * DKV + lg * 8;
    short8 qf0 = *(const short8*)qp;
    short8 qf1 = *(const short8*)(qp + 32);
    float m = -1e30f;
    f32x4 oacc[4] = {};
    f32x4 oext = {};
    int nt = qt + 1;

    short8 kr0 = *(const short8*)kb0;
    short8 kr1 = *(const short8*)kb1;
    short8 vr0 = *(const short8*)vb0;
    short8 vr1 = *(const short8*)vb1;
    *(short8*)&Ks[0][sr][sp0] = kr0;
    *(short8*)&Ks[0][sr][sp1] = kr1;
    *(short8*)&Vt[0][sr][sp0] = vr0;
    *(short8*)&Vt[0][sr][sp1] = vr1;
    if (nt > 1) {
        kr0 = *(const short8*)(kb0 + (size_t)64 * 2048);
        kr1 = *(const short8*)(kb1 + (size_t)64 * 2048);
        vr0 = *(const short8*)(vb0 + 64);
        vr1 = *(const short8*)(vb1 + 64);
    }
    __syncthreads();

    for (int t = 0; t < nt; ++t) {
        int nb = (t + 1) & 1;
        if (t + 1 < nt) {
            *(short8*)&Ks[nb][sr][sp0] = kr0;
            *(short8*)&Ks[nb][sr][sp1] = kr1;
            *(short8*)&Vt[nb][sr][sp0] = vr0;
            *(short8*)&Vt[nb][sr][sp1] = vr1;
            if (t + 2 < nt) {
                kr0 = *(const short8*)(kb0 + (size_t)(t + 2) * 64 * 2048);
                kr1 = *(const short8*)(kb1 + (size_t)(t + 2) * 64 * 2048);
                vr0 = *(const short8*)(vb0 + (t + 2) * 64);
                vr1 = *(const short8*)(vb1 + (t + 2) * 64);
            }
        }
        int bu = t & 1;

        f32x4 sc[4] = {};
        __builtin_amdgcn_s_setprio(1);
        #pragma unroll
        for (int st = 0; st < 4; ++st) {
            short8 kf0 = *(const short8*)&Ks[bu][st * 16 + l15][rk0];
            sc[st] = __builtin_amdgcn_mfma_f32_16x16x32_bf16(kf0, qf0, sc[st], 0, 0, 0);
            short8 kf1 = *(const short8*)&Ks[bu][st * 16 + l15][rk1];
            sc[st] = __builtin_amdgcn_mfma_f32_16x16x32_bf16(kf1, qf1, sc[st], 0, 0, 0);
        }
        __builtin_amdgcn_s_setprio(0);

        float pv[4][4];
        float pmax = -1e30f;
        if (t == qt) {
            int klim = qrow - t * 64;
            #pragma unroll
            for (int st = 0; st < 4; ++st) {
                #pragma unroll
                for (int j = 0; j < 4; ++j) {
                    float s = sc[st][j];
                    if (st * 16 + lg * 4 + j > klim) s = -1e30f;
                    pv[st][j] = s;
                    pmax = fmaxf(pmax, s);
                }
            }
        } else {
            #pragma unroll
            for (int st = 0; st < 4; ++st) {
                #pragma unroll
                for (int j = 0; j < 4; ++j) {
                    pv[st][j] = sc[st][j];
                    pmax = fmaxf(pmax, sc[st][j]);
                }
            }
        }

        if (!__all(pmax - m <= 8.0f)) {
            float pr = fmaxf(pmax, __shfl_xor(pmax, 16, 64));
            pr = fmaxf(pr, __shfl_xor(pr, 32, 64));
            float mn = fmaxf(m, pr);
            float scl2 = exp2f(m - mn);
            #pragma unroll
            for (int d = 0; d < 4; ++d)
                #pragma unroll
                for (int j = 0; j < 4; ++j)
                    oacc[d][j] *= scl2;
            #pragma unroll
            for (int j = 0; j < 4; ++j) oext[j] *= scl2;
            m = mn;
        }

        #pragma unroll
        for (int st = 0; st < 4; ++st) {
            float p0 = exp2f(pv[st][0] - m);
            float p1 = exp2f(pv[st][1] - m);
            float p2 = exp2f(pv[st][2] - m);
            float p3 = exp2f(pv[st][3] - m);
            unsigned int ua, ub;
            asm("v_cvt_pk_bf16_f32 %0, %1, %2" : "=v"(ua) : "v"(p0), "v"(p1));
            asm("v_cvt_pk_bf16_f32 %0, %1, %2" : "=v"(ub) : "v"(p2), "v"(p3));
            uint2 u = make_uint2(ua, ub);
            *(uint2*)&Ps[w][l15][st * 16 + lg * 4] = u;
        }

        __builtin_amdgcn_s_setprio(1);
        #pragma unroll
        for (int ks = 0; ks < 2; ++ks) {
            short8 pf = *(const short8*)&Ps[w][l15][ks * 32 + lg * 8];
            int rv = (ks == 0) ? rk0 : rk1;
            #pragma unroll
            for (int d = 0; d < 4; ++d) {
                short8 vf = *(const short8*)&Vt[bu][d * 16 + l15][rv];
                oacc[d] = __builtin_amdgcn_mfma_f32_16x16x32_bf16(vf, pf, oacc[d], 0, 0, 0);
            }
            oext = __builtin_amdgcn_mfma_f32_16x16x32_bf16(vf5, pf, oext, 0, 0, 0);
        }
        __builtin_amdgcn_s_setprio(0);
        __syncthreads();
    }

    float lsum = __shfl(oext[0], l15, 64);
    float inv = 1.0f / lsum;
    size_t ob = (size_t)(b * SEQ + qrow) * H_DIM + h * DKV;
    #pragma unroll
    for (int d = 0; d < 4; ++d) {
        float o0 = oacc[d][0] * inv, o1 = oacc[d][1] * inv;
        float o2 = oacc[d][2] * inv, o3 = oacc[d][3] * inv;
        unsigned int ua, ub;
        asm("v_cvt_pk_bf16_f32 %0, %1, %2" : "=v"(ua) : "v"(o0), "v"(o1));
        asm("v_cvt_pk_bf16_f32 %0, %1, %2" : "=v"(ub) : "v"(o2), "v"(o3));
        *(uint2*)&out[ob + d * 16 + lg * 4] = make_uint2(ua, ub);
    }
}

// ---------------- launch ----------------
extern "C" void kernel_launch(void* const* d_in, const int* in_sizes, int n_in,
                              void* d_out, int out_size, void* d_ws, size_t ws_size,
                              hipStream_t stream) {
    const float* x     = (const float*)d_in[0];
    const float* ln1w  = (const float*)d_in[1];
    const float* ln1b  = (const float*)d_in[2];
    const float* Wqkv  = (const float*)d_in[3];
    const float* bqkv  = (const float*)d_in[4];
    const float* Wo    = (const float*)d_in[5];
    const float* bo    = (const float*)d_in[6];
    const float* ln2w  = (const float*)d_in[7];
    const float* ln2b  = (const float*)d_in[8];
    const float* Wfc   = (const float*)d_in[9];
    const float* bfc   = (const float*)d_in[10];
    const float* Wproj = (const float*)d_in[11];
    const float* bproj = (const float*)d_in[12];
    float* out = (float*)d_out;

    char* ws = (char*)d_ws;
    size_t off = 0;
    auto take = [&](size_t bytes) {
        void* p = ws + off;
        off += (bytes + 255) & ~(size_t)255;
        return p;
    };

    unsigned short* WqT  = (unsigned short*)take((size_t)3072 * 1024 * 2);
    unsigned short* WoT  = (unsigned short*)take((size_t)1024 * 1024 * 2);
    unsigned short* WfcT = (unsigned short*)take((size_t)4096 * 1024 * 2);
    unsigned short* WpT  = (unsigned short*)take((size_t)1024 * 4096 * 2);
    unsigned short* xn1   = (unsigned short*)take((size_t)ROWS * 1024 * 2);
    unsigned short* qk_h  = (unsigned short*)take((size_t)ROWS * 2048 * 2);
    unsigned short* vT    = (unsigned short*)take((size_t)ROWS * 1024 * 2);
    unsigned short* attn  = (unsigned short*)take((size_t)ROWS * 1024 * 2);
    unsigned short* x1h   = (unsigned short*)take((size_t)ROWS * 1024 * 2);
    unsigned short* xn2   = (unsigned short*)take((size_t)ROWS * 1024 * 2);
    unsigned short* hbuf  = (unsigned short*)take((size_t)ROWS * 4096 * 2);

    // all 4 weight transposes in ONE launch (12288 tiles)
    transpose_all<<<12288, 256, 0, stream>>>(Wqkv, Wo, Wfc, Wproj, WqT, WoT, WfcT, WpT);

    // LN1 (fp32 in) -> xn1
    ln_any<0><<<ROWS, 256, 0, stream>>>(x, ln1w, ln1b, xn1);

    // QKV: Q (pre-scaled) | K -> qk_h, V -> vT   (grid 768; XCD chunk 8x12)
    gemmT<4, 4><<<768, 512, 0, stream>>>(xn1, WqT, bqkv, nullptr, nullptr, qk_h, vT, 8, 12, 2, 3072, 1024);

    // causal attention -> attn (bf16), unpaired q-tiles, grid 1024 x 256 thr
    attn_mfma<<<1024, 256, 0, stream>>>(qk_h, vT, attn);

    // x1h = bf16(x + attn @ Wo + bo)
    gemmT<5, 2><<<512, 512, 0, stream>>>(attn, WoT, bo, x, nullptr, x1h, nullptr, 4, 16, 1, 1024, 1024);

    // LN2 (bf16 in) -> xn2
    ln_any<1><<<ROWS, 256, 0, stream>>>(x1h, ln2w, ln2b, xn2);

    // h = gelu(xn2 @ Wfc + bfc)   (grid 1024; XCD chunk 8x16)
    gemmT<2, 4><<<1024, 512, 0, stream>>>(xn2, WfcT, bfc, nullptr, nullptr, hbuf, nullptr, 8, 16, 2, 4096, 1024);

    // out = x1h + h @ Wproj + bproj
    gemmT<6, 2><<<512, 512, 0, stream>>>(hbuf, WpT, bproj, nullptr, out, nullptr, x1h, 4, 16, 1, 1024, 4096);
}

// Round 23
// 213.784 us; speedup vs baseline: 1.0655x; 1.0655x over previous
//
#include <hip/hip_runtime.h>
#include <hip/hip_bf16.h>
#include <math.h>

#define H_DIM 1024
#define SEQ   2048
#define BATCH 2
#define NHEAD 16
#define DKV   64
#define ROWS  (BATCH*SEQ)   // 4096
#define QSCALE 0.18033688f  // 0.125 * log2(e): scores land in log2 domain

typedef __attribute__((ext_vector_type(8))) short short8;
typedef __attribute__((ext_vector_type(4))) float f32x4;

static __device__ __forceinline__ unsigned short f32_bf16(float f) {
    unsigned int u = __builtin_bit_cast(unsigned int, f);
    u += 0x7FFF + ((u >> 16) & 1);          // RNE
    return (unsigned short)(u >> 16);
}
static __device__ __forceinline__ float bf16_f32(unsigned short h) {
    return __builtin_bit_cast(float, (unsigned int)h << 16);
}

// A&S 7.1.26 rational-poly erf, |err| < 1.5e-7
static __device__ __forceinline__ float fast_erf(float x) {
    float ax = fabsf(x);
    float t = 1.0f / fmaf(0.3275911f, ax, 1.0f);
    float p = t * fmaf(t, fmaf(t, fmaf(t, fmaf(t, 1.061405429f, -1.453152027f),
                                       1.421413741f), -0.284496736f), 0.254829592f);
    float y = fmaf(-p, __expf(-ax * ax), 1.0f);
    return copysignf(y, x);
}

static __device__ __forceinline__ void gload16(const unsigned short* g, unsigned short* l) {
    __builtin_amdgcn_global_load_lds(
        (const __attribute__((address_space(1))) void*)g,
        (__attribute__((address_space(3))) void*)l,
        16, 0, 0);
}

// ---------------- fused fp32 [K][N] -> bf16 [N][K] transpose for ALL 4 weights ----------------
__global__ __launch_bounds__(256) void transpose_all(const float* __restrict__ Wqkv,
                                                     const float* __restrict__ Wo,
                                                     const float* __restrict__ Wfc,
                                                     const float* __restrict__ Wproj,
                                                     unsigned short* __restrict__ WqT,
                                                     unsigned short* __restrict__ WoT,
                                                     unsigned short* __restrict__ WfcT,
                                                     unsigned short* __restrict__ WpT) {
    int t = blockIdx.x;
    const float* in; unsigned short* out; int K, N;
    if (t < 3072)      { in = Wqkv;  out = WqT;  K = 1024; N = 3072; }
    else if (t < 4096) { in = Wo;    out = WoT;  K = 1024; N = 1024; t -= 3072; }
    else if (t < 8192) { in = Wfc;   out = WfcT; K = 1024; N = 4096; t -= 4096; }
    else               { in = Wproj; out = WpT;  K = 4096; N = 1024; t -= 8192; }
    int ntx = N >> 5;
    int n0 = (t % ntx) * 32, k0 = (t / ntx) * 32;

    __shared__ float tile[32][33];
    int tx = threadIdx.x & 31, ty = threadIdx.x >> 5;   // 32 x 8
    #pragma unroll
    for (int i = 0; i < 4; ++i)
        tile[ty + i * 8][tx] = in[(size_t)(k0 + ty + i * 8) * N + n0 + tx];
    __syncthreads();
    #pragma unroll
    for (int i = 0; i < 4; ++i)
        out[(size_t)(n0 + ty + i * 8) * K + k0 + tx] = f32_bf16(tile[tx][ty + i * 8]);
}

// ---------------- LayerNorm (fp32 or bf16 in -> bf16 out) ----------------
template<int BF16IN>
__global__ __launch_bounds__(256) void ln_any(const void* __restrict__ xin,
                                              const float* __restrict__ w,
                                              const float* __restrict__ bb,
                                              unsigned short* __restrict__ out) {
    int row = blockIdx.x;
    int tid = threadIdx.x;
    float4 v;
    if (BF16IN) {
        ushort4 u = ((const ushort4*)((const unsigned short*)xin + (size_t)row * H_DIM))[tid];
        v.x = bf16_f32(u.x); v.y = bf16_f32(u.y); v.z = bf16_f32(u.z); v.w = bf16_f32(u.w);
    } else {
        v = ((const float4*)((const float*)xin + (size_t)row * H_DIM))[tid];
    }
    float s  = v.x + v.y + v.z + v.w;
    float s2 = v.x*v.x + v.y*v.y + v.z*v.z + v.w*v.w;
    #pragma unroll
    for (int off = 1; off < 64; off <<= 1) {
        s  += __shfl_xor(s,  off, 64);
        s2 += __shfl_xor(s2, off, 64);
    }
    __shared__ float red[8];
    int wv = tid >> 6;
    if ((tid & 63) == 0) { red[wv] = s; red[4 + wv] = s2; }
    __syncthreads();
    s  = red[0] + red[1] + red[2] + red[3];
    s2 = red[4] + red[5] + red[6] + red[7];
    float mu = s * (1.0f / H_DIM);
    float rs = rsqrtf(s2 * (1.0f / H_DIM) - mu * mu + 1e-5f);
    float4 wv4 = ((const float4*)w)[tid];
    float4 bv4 = ((const float4*)bb)[tid];
    ushort4 o;
    o.x = f32_bf16((v.x - mu) * rs * wv4.x + bv4.x);
    o.y = f32_bf16((v.y - mu) * rs * wv4.y + bv4.y);
    o.z = f32_bf16((v.z - mu) * rs * wv4.z + bv4.z);
    o.w = f32_bf16((v.w - mu) * rs * wv4.w + bv4.w);
    ((ushort4*)(out + (size_t)row * H_DIM))[tid] = o;
}

// ======== epilogue helper ========
template<int EPI>
static __device__ __forceinline__ void epi_store(f32x4 a, int row0, int col, int N,
                                                 const float* __restrict__ bias,
                                                 const float* __restrict__ resid,
                                                 float* __restrict__ outF,
                                                 unsigned short* __restrict__ outH,
                                                 unsigned short* __restrict__ outH2) {
    float bv = bias[col];
    if (EPI == 4 && col >= 2048) {
        int bb = row0 >> 11, ss = row0 & 2047;
        int hd = col - 2048;
        ushort4 u;
        u.x = f32_bf16(a[0] + bv);
        u.y = f32_bf16(a[1] + bv);
        u.z = f32_bf16(a[2] + bv);
        u.w = f32_bf16(a[3] + bv);
        *(ushort4*)&outH2[((size_t)bb * 1024 + hd) * SEQ + ss] = u;
    } else {
        #pragma unroll
        for (int j = 0; j < 4; ++j) {
            int row = row0 + j;
            size_t idx = (size_t)row * N + col;
            float c = a[j] + bv;
            if (EPI == 0) {
                outF[idx] = c;
            } else if (EPI == 1) {
                outF[idx] = resid[idx] + c;
            } else if (EPI == 2) {
                float g = 0.5f * c * (1.0f + fast_erf(c * 0.70710678118f));
                outH[idx] = f32_bf16(g);
            } else if (EPI == 3) {
                outH[idx] = f32_bf16(c);
            } else if (EPI == 5) {
                outH[idx] = f32_bf16(resid[idx] + c);
            } else if (EPI == 6) {
                outF[idx] = bf16_f32(outH2[idx]) + c;
            } else {
                float c2 = (col < 1024) ? c * QSCALE : c;
                outH[(size_t)row * 2048 + col] = f32_bf16(c2);
            }
        }
    }
}

// ---------------- bf16 MFMA GEMM, 128 x (NI*32) tile, BK=64, single-buffer,
//                  8 waves, wave-tile 64 x (NI*8); 2D XCD chunking (round-17 proven) ------
template<int EPI, int NI>
__global__ __launch_bounds__(512) void gemmT(const unsigned short* __restrict__ A,
                                             const unsigned short* __restrict__ Bt,
                                             const float* __restrict__ bias,
                                             const float* __restrict__ resid,
                                             float* __restrict__ outF,
                                             unsigned short* __restrict__ outH,
                                             unsigned short* __restrict__ outH2,
                                             int cm, int cn, int ncc, int N, int K) {
    constexpr int BN = NI * 32;
    constexpr int WN = BN / 4;
    constexpr int NT = WN / 16;
    __shared__ __attribute__((aligned(16))) unsigned short As[128][64];
    __shared__ __attribute__((aligned(16))) unsigned short Bs[BN][64];
    int tid = threadIdx.x;
    int w = tid >> 6, l = tid & 63;
    int l15 = l & 15, lg = l >> 4;
    int wm = w & 1, wn = w >> 1;

    int c = blockIdx.x & 7, lwg = blockIdx.x >> 3;
    int lm = lwg / cn, ln = lwg - lm * cn;
    int ccr = c / ncc;
    int bm = ccr * cm + lm;
    int bn = (c - ccr * ncc) * cn + ln;
    int m0 = bm * 128, n0 = bn * BN;

    f32x4 acc[4][NT] = {};

    const unsigned short* aptr[2];
    unsigned short* lA[2];
    #pragma unroll
    for (int j = 0; j < 2; ++j) {
        int slot = j * 512 + tid;
        int row = slot >> 3;
        int lchunk = (slot & 7) ^ (row & 7);
        aptr[j] = A + (size_t)(m0 + row) * K + lchunk * 8;
        lA[j] = &As[0][0] + (size_t)slot * 8 - l * 8;
    }
    const unsigned short* bptr[NI / 2];
    unsigned short* lB[NI / 2];
    #pragma unroll
    for (int j = 0; j < NI / 2; ++j) {
        int slot = j * 512 + tid;
        int row = slot >> 3;
        int lchunk = (slot & 7) ^ (row & 7);
        bptr[j] = Bt + (size_t)(n0 + row) * K + lchunk * 8;
        lB[j] = &Bs[0][0] + (size_t)slot * 8 - l * 8;
    }
    int swz[2];
    swz[0] = ((0 + lg) ^ (l15 & 7)) * 8;
    swz[1] = ((4 + lg) ^ (l15 & 7)) * 8;
    const unsigned short* pA = &As[wm * 64 + l15][0];
    const unsigned short* pB = &Bs[wn * WN + l15][0];

    for (int k0 = 0; k0 < K; k0 += 64) {
        __syncthreads();
        #pragma unroll
        for (int j = 0; j < 2; ++j) gload16(aptr[j] + k0, lA[j]);
        #pragma unroll
        for (int j = 0; j < NI / 2; ++j) gload16(bptr[j] + k0, lB[j]);
        __syncthreads();

        #pragma unroll
        for (int ks = 0; ks < 2; ++ks) {
            short8 af[4], bf[NT];
            #pragma unroll
            for (int mi = 0; mi < 4; ++mi)
                af[mi] = *(const short8*)(pA + mi * 16 * 64 + swz[ks]);
            #pragma unroll
            for (int ni = 0; ni < NT; ++ni)
                bf[ni] = *(const short8*)(pB + ni * 16 * 64 + swz[ks]);
            #pragma unroll
            for (int mi = 0; mi < 4; ++mi)
                #pragma unroll
                for (int ni = 0; ni < NT; ++ni)
                    acc[mi][ni] = __builtin_amdgcn_mfma_f32_16x16x32_bf16(af[mi], bf[ni], acc[mi][ni], 0, 0, 0);
        }
    }

    #pragma unroll
    for (int mi = 0; mi < 4; ++mi)
        #pragma unroll
        for (int ni = 0; ni < NT; ++ni)
            epi_store<EPI>(acc[mi][ni], m0 + wm * 64 + mi * 16 + lg * 4,
                           n0 + wn * WN + ni * 16 + l15, N, bias, resid, outF, outH, outH2);
}

// ---------------- causal flash attention: QBLK=64, 4 waves, PAIRED q-tiles (p, 31-p),
//                  two sequential passes (round-19/21 proven best) ----------------
__global__ __launch_bounds__(256) void attn_mfma(const unsigned short* __restrict__ qk,
                                                 const unsigned short* __restrict__ vT,
                                                 unsigned short* __restrict__ out) {
    int bid = blockIdx.x;
    int swz = (bid & 7) * 64 + (bid >> 3);    // 512 % 8 == 0 -> bijective
    int b  = swz >> 8;
    int h  = (swz >> 4) & 15;
    int p  = swz & 15;                        // pair: q-tiles p and 31-p
    int tid = threadIdx.x;
    int w = tid >> 6, l = tid & 63;
    int l15 = l & 15, lg = l >> 4;

    __shared__ __attribute__((aligned(16))) unsigned short Ks[2][64][64];
    __shared__ __attribute__((aligned(16))) unsigned short Vt[2][64][64];
    __shared__ __attribute__((aligned(16))) unsigned short Ps[4][16][72];

    short8 vf5;
    #pragma unroll
    for (int i = 0; i < 8; ++i) vf5[i] = (l15 == 0) ? (short)0x3F80 : (short)0;

    int sr = tid >> 2;                        // 0..63
    int c0 = (tid & 3) * 2, c1 = c0 + 1;
    int sp0 = ((c0 ^ (sr & 7)) * 8);
    int sp1 = ((c1 ^ (sr & 7)) * 8);
    const unsigned short* kb0 = qk + (size_t)(b * SEQ + sr) * 2048 + 1024 + h * DKV + c0 * 8;
    const unsigned short* kb1 = kb0 + 8;
    const unsigned short* vb0 = vT + ((size_t)(b * NHEAD + h) * DKV + sr) * SEQ + c0 * 8;
    const unsigned short* vb1 = vb0 + 8;

    int rk0 = ((0 + lg) ^ (l15 & 7)) * 8;
    int rk1 = ((4 + lg) ^ (l15 & 7)) * 8;

    auto run_pass = [&](int qt) {
        int qrow = qt * 64 + w * 16 + l15;
        const unsigned short* qp = qk + (size_t)(b * SEQ + qrow) * 2048 + h * DKV + lg * 8;
        short8 qf0 = *(const short8*)qp;
        short8 qf1 = *(const short8*)(qp + 32);
        float m = -1e30f;
        f32x4 oacc[4] = {};
        f32x4 oext = {};
        int nt = qt + 1;

        short8 kr0 = *(const short8*)kb0;
        short8 kr1 = *(const short8*)kb1;
        short8 vr0 = *(const short8*)vb0;
        short8 vr1 = *(const short8*)vb1;
        *(short8*)&Ks[0][sr][sp0] = kr0;
        *(short8*)&Ks[0][sr][sp1] = kr1;
        *(short8*)&Vt[0][sr][sp0] = vr0;
        *(short8*)&Vt[0][sr][sp1] = vr1;
        if (nt > 1) {
            kr0 = *(const short8*)(kb0 + (size_t)64 * 2048);
            kr1 = *(const short8*)(kb1 + (size_t)64 * 2048);
            vr0 = *(const short8*)(vb0 + 64);
            vr1 = *(const short8*)(vb1 + 64);
        }
        __syncthreads();

        for (int t = 0; t < nt; ++t) {
            int nb = (t + 1) & 1;
            if (t + 1 < nt) {
                *(short8*)&Ks[nb][sr][sp0] = kr0;
                *(short8*)&Ks[nb][sr][sp1] = kr1;
                *(short8*)&Vt[nb][sr][sp0] = vr0;
                *(short8*)&Vt[nb][sr][sp1] = vr1;
                if (t + 2 < nt) {
                    kr0 = *(const short8*)(kb0 + (size_t)(t + 2) * 64 * 2048);
                    kr1 = *(const short8*)(kb1 + (size_t)(t + 2) * 64 * 2048);
                    vr0 = *(const short8*)(vb0 + (t + 2) * 64);
                    vr1 = *(const short8*)(vb1 + (t + 2) * 64);
                }
            }
            int bu = t & 1;

            f32x4 sc[4] = {};
            __builtin_amdgcn_s_setprio(1);
            #pragma unroll
            for (int st = 0; st < 4; ++st) {
                short8 kf0 = *(const short8*)&Ks[bu][st * 16 + l15][rk0];
                sc[st] = __builtin_amdgcn_mfma_f32_16x16x32_bf16(kf0, qf0, sc[st], 0, 0, 0);
                short8 kf1 = *(const short8*)&Ks[bu][st * 16 + l15][rk1];
                sc[st] = __builtin_amdgcn_mfma_f32_16x16x32_bf16(kf1, qf1, sc[st], 0, 0, 0);
            }
            __builtin_amdgcn_s_setprio(0);

            float pv[4][4];
            float pmax = -1e30f;
            if (t == qt) {
                int klim = qrow - t * 64;
                #pragma unroll
                for (int st = 0; st < 4; ++st) {
                    #pragma unroll
                    for (int j = 0; j < 4; ++j) {
                        float s = sc[st][j];
                        if (st * 16 + lg * 4 + j > klim) s = -1e30f;
                        pv[st][j] = s;
                        pmax = fmaxf(pmax, s);
                    }
                }
            } else {
                #pragma unroll
                for (int st = 0; st < 4; ++st) {
                    #pragma unroll
                    for (int j = 0; j < 4; ++j) {
                        pv[st][j] = sc[st][j];
                        pmax = fmaxf(pmax, sc[st][j]);
                    }
                }
            }

            if (!__all(pmax - m <= 8.0f)) {
                float pr = fmaxf(pmax, __shfl_xor(pmax, 16, 64));
                pr = fmaxf(pr, __shfl_xor(pr, 32, 64));
                float mn = fmaxf(m, pr);
                float scl2 = exp2f(m - mn);
                #pragma unroll
                for (int d = 0; d < 4; ++d)
                    #pragma unroll
                    for (int j = 0; j < 4; ++j)
                        oacc[d][j] *= scl2;
                #pragma unroll
                for (int j = 0; j < 4; ++j) oext[j] *= scl2;
                m = mn;
            }

            #pragma unroll
            for (int st = 0; st < 4; ++st) {
                float p0 = exp2f(pv[st][0] - m);
                float p1 = exp2f(pv[st][1] - m);
                float p2 = exp2f(pv[st][2] - m);
                float p3 = exp2f(pv[st][3] - m);
                unsigned int ua, ub;
                asm("v_cvt_pk_bf16_f32 %0, %1, %2" : "=v"(ua) : "v"(p0), "v"(p1));
                asm("v_cvt_pk_bf16_f32 %0, %1, %2" : "=v"(ub) : "v"(p2), "v"(p3));
                uint2 u = make_uint2(ua, ub);
                *(uint2*)&Ps[w][l15][st * 16 + lg * 4] = u;
            }

            __builtin_amdgcn_s_setprio(1);
            #pragma unroll
            for (int ks = 0; ks < 2; ++ks) {
                short8 pf = *(const short8*)&Ps[w][l15][ks * 32 + lg * 8];
                int rv = (ks == 0) ? rk0 : rk1;
                #pragma unroll
                for (int d = 0; d < 4; ++d) {
                    short8 vf = *(const short8*)&Vt[bu][d * 16 + l15][rv];
                    oacc[d] = __builtin_amdgcn_mfma_f32_16x16x32_bf16(vf, pf, oacc[d], 0, 0, 0);
                }
                oext = __builtin_amdgcn_mfma_f32_16x16x32_bf16(vf5, pf, oext, 0, 0, 0);
            }
            __builtin_amdgcn_s_setprio(0);
            __syncthreads();
        }

        float lsum = __shfl(oext[0], l15, 64);
        float inv = 1.0f / lsum;
        size_t ob = (size_t)(b * SEQ + qrow) * H_DIM + h * DKV;
        #pragma unroll
        for (int d = 0; d < 4; ++d) {
            float o0 = oacc[d][0] * inv, o1 = oacc[d][1] * inv;
            float o2 = oacc[d][2] * inv, o3 = oacc[d][3] * inv;
            unsigned int ua, ub;
            asm("v_cvt_pk_bf16_f32 %0, %1, %2" : "=v"(ua) : "v"(o0), "v"(o1));
            asm("v_cvt_pk_bf16_f32 %0, %1, %2" : "=v"(ub) : "v"(o2), "v"(o3));
            *(uint2*)&out[ob + d * 16 + lg * 4] = make_uint2(ua, ub);
        }
    };

    run_pass(31 - p);   // long half first
    run_pass(p);        // short half
}

// ---------------- launch ----------------
extern "C" void kernel_launch(void* const* d_in, const int* in_sizes, int n_in,
                              void* d_out, int out_size, void* d_ws, size_t ws_size,
                              hipStream_t stream) {
    const float* x     = (const float*)d_in[0];
    const float* ln1w  = (const float*)d_in[1];
    const float* ln1b  = (const float*)d_in[2];
    const float* Wqkv  = (const float*)d_in[3];
    const float* bqkv  = (const float*)d_in[4];
    const float* Wo    = (const float*)d_in[5];
    const float* bo    = (const float*)d_in[6];
    const float* ln2w  = (const float*)d_in[7];
    const float* ln2b  = (const float*)d_in[8];
    const float* Wfc   = (const float*)d_in[9];
    const float* bfc   = (const float*)d_in[10];
    const float* Wproj = (const float*)d_in[11];
    const float* bproj = (const float*)d_in[12];
    float* out = (float*)d_out;

    char* ws = (char*)d_ws;
    size_t off = 0;
    auto take = [&](size_t bytes) {
        void* p = ws + off;
        off += (bytes + 255) & ~(size_t)255;
        return p;
    };

    unsigned short* WqT  = (unsigned short*)take((size_t)3072 * 1024 * 2);
    unsigned short* WoT  = (unsigned short*)take((size_t)1024 * 1024 * 2);
    unsigned short* WfcT = (unsigned short*)take((size_t)4096 * 1024 * 2);
    unsigned short* WpT  = (unsigned short*)take((size_t)1024 * 4096 * 2);
    unsigned short* xn1   = (unsigned short*)take((size_t)ROWS * 1024 * 2);
    unsigned short* qk_h  = (unsigned short*)take((size_t)ROWS * 2048 * 2);
    unsigned short* vT    = (unsigned short*)take((size_t)ROWS * 1024 * 2);
    unsigned short* attn  = (unsigned short*)take((size_t)ROWS * 1024 * 2);
    unsigned short* x1h   = (unsigned short*)take((size_t)ROWS * 1024 * 2);
    unsigned short* xn2   = (unsigned short*)take((size_t)ROWS * 1024 * 2);
    unsigned short* hbuf  = (unsigned short*)take((size_t)ROWS * 4096 * 2);

    // all 4 weight transposes in ONE launch (12288 tiles)
    transpose_all<<<12288, 256, 0, stream>>>(Wqkv, Wo, Wfc, Wproj, WqT, WoT, WfcT, WpT);

    // LN1 (fp32 in) -> xn1
    ln_any<0><<<ROWS, 256, 0, stream>>>(x, ln1w, ln1b, xn1);

    // QKV: Q (pre-scaled) | K -> qk_h, V -> vT   (grid 768; XCD chunk 8x12)
    gemmT<4, 4><<<768, 512, 0, stream>>>(xn1, WqT, bqkv, nullptr, nullptr, qk_h, vT, 8, 12, 2, 3072, 1024);

    // causal attention -> attn (bf16), paired q-tiles, grid 512 x 256 thr
    attn_mfma<<<512, 256, 0, stream>>>(qk_h, vT, attn);

    // x1h = bf16(x + attn @ Wo + bo)
    gemmT<5, 2><<<512, 512, 0, stream>>>(attn, WoT, bo, x, nullptr, x1h, nullptr, 4, 16, 1, 1024, 1024);

    // LN2 (bf16 in) -> xn2
    ln_any<1><<<ROWS, 256, 0, stream>>>(x1h, ln2w, ln2b, xn2);

    // h = gelu(xn2 @ Wfc + bfc)   (grid 1024; XCD chunk 8x16)
    gemmT<2, 4><<<1024, 512, 0, stream>>>(xn2, WfcT, bfc, nullptr, nullptr, hbuf, nullptr, 8, 16, 2, 4096, 1024);

    // out = x1h + h @ Wproj + bproj
    gemmT<6, 2><<<512, 512, 0, stream>>>(hbuf, WpT, bproj, nullptr, out, nullptr, x1h, 4, 16, 1, 1024, 4096);
}

// Round 24
// 212.620 us; speedup vs baseline: 1.0714x; 1.0055x over previous
//
#include <hip/hip_runtime.h>
#include <hip/hip_bf16.h>
#include <math.h>

#define H_DIM 1024
#define SEQ   2048
#define BATCH 2
#define NHEAD 16
#define DKV   64
#define ROWS  (BATCH*SEQ)   // 4096
#define QSCALE 0.18033688f  // 0.125 * log2(e): scores land in log2 domain

typedef __attribute__((ext_vector_type(8))) short short8;
typedef __attribute__((ext_vector_type(4))) float f32x4;

static __device__ __forceinline__ unsigned short f32_bf16(float f) {
    unsigned int u = __builtin_bit_cast(unsigned int, f);
    u += 0x7FFF + ((u >> 16) & 1);          // RNE
    return (unsigned short)(u >> 16);
}
static __device__ __forceinline__ float bf16_f32(unsigned short h) {
    return __builtin_bit_cast(float, (unsigned int)h << 16);
}

// A&S 7.1.26 rational-poly erf, |err| < 1.5e-7
static __device__ __forceinline__ float fast_erf(float x) {
    float ax = fabsf(x);
    float t = 1.0f / fmaf(0.3275911f, ax, 1.0f);
    float p = t * fmaf(t, fmaf(t, fmaf(t, fmaf(t, 1.061405429f, -1.453152027f),
                                       1.421413741f), -0.284496736f), 0.254829592f);
    float y = fmaf(-p, __expf(-ax * ax), 1.0f);
    return copysignf(y, x);
}

static __device__ __forceinline__ void gload16(const unsigned short* g, unsigned short* l) {
    __builtin_amdgcn_global_load_lds(
        (const __attribute__((address_space(1))) void*)g,
        (__attribute__((address_space(3))) void*)l,
        16, 0, 0);
}

// ---------------- fused: 4 weight transposes (blocks 0..12287) + LN1 (12288..16383) ----------------
__global__ __launch_bounds__(256) void prep_all(const float* __restrict__ Wqkv,
                                                const float* __restrict__ Wo,
                                                const float* __restrict__ Wfc,
                                                const float* __restrict__ Wproj,
                                                unsigned short* __restrict__ WqT,
                                                unsigned short* __restrict__ WoT,
                                                unsigned short* __restrict__ WfcT,
                                                unsigned short* __restrict__ WpT,
                                                const float* __restrict__ x,
                                                const float* __restrict__ ln1w,
                                                const float* __restrict__ ln1b,
                                                unsigned short* __restrict__ xn1) {
    int t = blockIdx.x;
    int tid = threadIdx.x;

    if (t >= 12288) {
        // ---- LN1 path (fp32 in -> bf16 out) ----
        int row = t - 12288;
        float4 v = ((const float4*)(x + (size_t)row * H_DIM))[tid];
        float s  = v.x + v.y + v.z + v.w;
        float s2 = v.x*v.x + v.y*v.y + v.z*v.z + v.w*v.w;
        #pragma unroll
        for (int off = 1; off < 64; off <<= 1) {
            s  += __shfl_xor(s,  off, 64);
            s2 += __shfl_xor(s2, off, 64);
        }
        __shared__ float red[8];
        int wv = tid >> 6;
        if ((tid & 63) == 0) { red[wv] = s; red[4 + wv] = s2; }
        __syncthreads();
        s  = red[0] + red[1] + red[2] + red[3];
        s2 = red[4] + red[5] + red[6] + red[7];
        float mu = s * (1.0f / H_DIM);
        float rs = rsqrtf(s2 * (1.0f / H_DIM) - mu * mu + 1e-5f);
        float4 wv4 = ((const float4*)ln1w)[tid];
        float4 bv4 = ((const float4*)ln1b)[tid];
        ushort4 o;
        o.x = f32_bf16((v.x - mu) * rs * wv4.x + bv4.x);
        o.y = f32_bf16((v.y - mu) * rs * wv4.y + bv4.y);
        o.z = f32_bf16((v.z - mu) * rs * wv4.z + bv4.z);
        o.w = f32_bf16((v.w - mu) * rs * wv4.w + bv4.w);
        ((ushort4*)(xn1 + (size_t)row * H_DIM))[tid] = o;
        return;
    }

    // ---- transpose path ----
    const float* in; unsigned short* out; int K, N;
    if (t < 3072)      { in = Wqkv;  out = WqT;  K = 1024; N = 3072; }
    else if (t < 4096) { in = Wo;    out = WoT;  K = 1024; N = 1024; t -= 3072; }
    else if (t < 8192) { in = Wfc;   out = WfcT; K = 1024; N = 4096; t -= 4096; }
    else               { in = Wproj; out = WpT;  K = 4096; N = 1024; t -= 8192; }
    int ntx = N >> 5;
    int n0 = (t % ntx) * 32, k0 = (t / ntx) * 32;

    __shared__ float tile[32][33];
    int tx = tid & 31, ty = tid >> 5;   // 32 x 8
    #pragma unroll
    for (int i = 0; i < 4; ++i)
        tile[ty + i * 8][tx] = in[(size_t)(k0 + ty + i * 8) * N + n0 + tx];
    __syncthreads();
    #pragma unroll
    for (int i = 0; i < 4; ++i)
        out[(size_t)(n0 + ty + i * 8) * K + k0 + tx] = f32_bf16(tile[tx][ty + i * 8]);
}

// ---------------- LayerNorm (bf16 in -> bf16 out) ----------------
__global__ __launch_bounds__(256) void ln_bf16in(const unsigned short* __restrict__ xin,
                                                 const float* __restrict__ w,
                                                 const float* __restrict__ bb,
                                                 unsigned short* __restrict__ out) {
    int row = blockIdx.x;
    int tid = threadIdx.x;
    float4 v;
    ushort4 u = ((const ushort4*)(xin + (size_t)row * H_DIM))[tid];
    v.x = bf16_f32(u.x); v.y = bf16_f32(u.y); v.z = bf16_f32(u.z); v.w = bf16_f32(u.w);
    float s  = v.x + v.y + v.z + v.w;
    float s2 = v.x*v.x + v.y*v.y + v.z*v.z + v.w*v.w;
    #pragma unroll
    for (int off = 1; off < 64; off <<= 1) {
        s  += __shfl_xor(s,  off, 64);
        s2 += __shfl_xor(s2, off, 64);
    }
    __shared__ float red[8];
    int wv = tid >> 6;
    if ((tid & 63) == 0) { red[wv] = s; red[4 + wv] = s2; }
    __syncthreads();
    s  = red[0] + red[1] + red[2] + red[3];
    s2 = red[4] + red[5] + red[6] + red[7];
    float mu = s * (1.0f / H_DIM);
    float rs = rsqrtf(s2 * (1.0f / H_DIM) - mu * mu + 1e-5f);
    float4 wv4 = ((const float4*)w)[tid];
    float4 bv4 = ((const float4*)bb)[tid];
    ushort4 o;
    o.x = f32_bf16((v.x - mu) * rs * wv4.x + bv4.x);
    o.y = f32_bf16((v.y - mu) * rs * wv4.y + bv4.y);
    o.z = f32_bf16((v.z - mu) * rs * wv4.z + bv4.z);
    o.w = f32_bf16((v.w - mu) * rs * wv4.w + bv4.w);
    ((ushort4*)(out + (size_t)row * H_DIM))[tid] = o;
}

// ======== epilogue helper ========
template<int EPI>
static __device__ __forceinline__ void epi_store(f32x4 a, int row0, int col, int N,
                                                 const float* __restrict__ bias,
                                                 const float* __restrict__ resid,
                                                 float* __restrict__ outF,
                                                 unsigned short* __restrict__ outH,
                                                 unsigned short* __restrict__ outH2) {
    float bv = bias[col];
    if (EPI == 4 && col >= 2048) {
        int bb = row0 >> 11, ss = row0 & 2047;
        int hd = col - 2048;
        ushort4 u;
        u.x = f32_bf16(a[0] + bv);
        u.y = f32_bf16(a[1] + bv);
        u.z = f32_bf16(a[2] + bv);
        u.w = f32_bf16(a[3] + bv);
        *(ushort4*)&outH2[((size_t)bb * 1024 + hd) * SEQ + ss] = u;
    } else {
        #pragma unroll
        for (int j = 0; j < 4; ++j) {
            int row = row0 + j;
            size_t idx = (size_t)row * N + col;
            float c = a[j] + bv;
            if (EPI == 0) {
                outF[idx] = c;
            } else if (EPI == 1) {
                outF[idx] = resid[idx] + c;
            } else if (EPI == 2) {
                float g = 0.5f * c * (1.0f + fast_erf(c * 0.70710678118f));
                outH[idx] = f32_bf16(g);
            } else if (EPI == 3) {
                outH[idx] = f32_bf16(c);
            } else if (EPI == 5) {
                outH[idx] = f32_bf16(resid[idx] + c);
            } else if (EPI == 6) {
                outF[idx] = bf16_f32(outH2[idx]) + c;
            } else {
                float c2 = (col < 1024) ? c * QSCALE : c;
                outH[(size_t)row * 2048 + col] = f32_bf16(c2);
            }
        }
    }
}

// ---------------- bf16 MFMA GEMM, 128 x (NI*32) tile, BK=64, single-buffer,
//                  8 waves, wave-tile 64 x (NI*8); 2D XCD chunking (round-17 proven) ------
template<int EPI, int NI>
__global__ __launch_bounds__(512) void gemmT(const unsigned short* __restrict__ A,
                                             const unsigned short* __restrict__ Bt,
                                             const float* __restrict__ bias,
                                             const float* __restrict__ resid,
                                             float* __restrict__ outF,
                                             unsigned short* __restrict__ outH,
                                             unsigned short* __restrict__ outH2,
                                             int cm, int cn, int ncc, int N, int K) {
    constexpr int BN = NI * 32;
    constexpr int WN = BN / 4;
    constexpr int NT = WN / 16;
    __shared__ __attribute__((aligned(16))) unsigned short As[128][64];
    __shared__ __attribute__((aligned(16))) unsigned short Bs[BN][64];
    int tid = threadIdx.x;
    int w = tid >> 6, l = tid & 63;
    int l15 = l & 15, lg = l >> 4;
    int wm = w & 1, wn = w >> 1;

    int c = blockIdx.x & 7, lwg = blockIdx.x >> 3;
    int lm = lwg / cn, ln = lwg - lm * cn;
    int ccr = c / ncc;
    int bm = ccr * cm + lm;
    int bn = (c - ccr * ncc) * cn + ln;
    int m0 = bm * 128, n0 = bn * BN;

    f32x4 acc[4][NT] = {};

    const unsigned short* aptr[2];
    unsigned short* lA[2];
    #pragma unroll
    for (int j = 0; j < 2; ++j) {
        int slot = j * 512 + tid;
        int row = slot >> 3;
        int lchunk = (slot & 7) ^ (row & 7);
        aptr[j] = A + (size_t)(m0 + row) * K + lchunk * 8;
        lA[j] = &As[0][0] + (size_t)slot * 8 - l * 8;
    }
    const unsigned short* bptr[NI / 2];
    unsigned short* lB[NI / 2];
    #pragma unroll
    for (int j = 0; j < NI / 2; ++j) {
        int slot = j * 512 + tid;
        int row = slot >> 3;
        int lchunk = (slot & 7) ^ (row & 7);
        bptr[j] = Bt + (size_t)(n0 + row) * K + lchunk * 8;
        lB[j] = &Bs[0][0] + (size_t)slot * 8 - l * 8;
    }
    int swz[2];
    swz[0] = ((0 + lg) ^ (l15 & 7)) * 8;
    swz[1] = ((4 + lg) ^ (l15 & 7)) * 8;
    const unsigned short* pA = &As[wm * 64 + l15][0];
    const unsigned short* pB = &Bs[wn * WN + l15][0];

    for (int k0 = 0; k0 < K; k0 += 64) {
        __syncthreads();
        #pragma unroll
        for (int j = 0; j < 2; ++j) gload16(aptr[j] + k0, lA[j]);
        #pragma unroll
        for (int j = 0; j < NI / 2; ++j) gload16(bptr[j] + k0, lB[j]);
        __syncthreads();

        #pragma unroll
        for (int ks = 0; ks < 2; ++ks) {
            short8 af[4], bf[NT];
            #pragma unroll
            for (int mi = 0; mi < 4; ++mi)
                af[mi] = *(const short8*)(pA + mi * 16 * 64 + swz[ks]);
            #pragma unroll
            for (int ni = 0; ni < NT; ++ni)
                bf[ni] = *(const short8*)(pB + ni * 16 * 64 + swz[ks]);
            #pragma unroll
            for (int mi = 0; mi < 4; ++mi)
                #pragma unroll
                for (int ni = 0; ni < NT; ++ni)
                    acc[mi][ni] = __builtin_amdgcn_mfma_f32_16x16x32_bf16(af[mi], bf[ni], acc[mi][ni], 0, 0, 0);
        }
    }

    #pragma unroll
    for (int mi = 0; mi < 4; ++mi)
        #pragma unroll
        for (int ni = 0; ni < NT; ++ni)
            epi_store<EPI>(acc[mi][ni], m0 + wm * 64 + mi * 16 + lg * 4,
                           n0 + wn * WN + ni * 16 + l15, N, bias, resid, outF, outH, outH2);
}

// ---------------- causal flash attention: QBLK=64, 4 waves, PAIRED q-tiles (p, 31-p),
//                  two sequential passes (round-19/21 proven best) ----------------
__global__ __launch_bounds__(256) void attn_mfma(const unsigned short* __restrict__ qk,
                                                 const unsigned short* __restrict__ vT,
                                                 unsigned short* __restrict__ out) {
    int bid = blockIdx.x;
    int swz = (bid & 7) * 64 + (bid >> 3);    // 512 % 8 == 0 -> bijective
    int b  = swz >> 8;
    int h  = (swz >> 4) & 15;
    int p  = swz & 15;                        // pair: q-tiles p and 31-p
    int tid = threadIdx.x;
    int w = tid >> 6, l = tid & 63;
    int l15 = l & 15, lg = l >> 4;

    __shared__ __attribute__((aligned(16))) unsigned short Ks[2][64][64];
    __shared__ __attribute__((aligned(16))) unsigned short Vt[2][64][64];
    __shared__ __attribute__((aligned(16))) unsigned short Ps[4][16][72];

    short8 vf5;
    #pragma unroll
    for (int i = 0; i < 8; ++i) vf5[i] = (l15 == 0) ? (short)0x3F80 : (short)0;

    int sr = tid >> 2;                        // 0..63
    int c0 = (tid & 3) * 2, c1 = c0 + 1;
    int sp0 = ((c0 ^ (sr & 7)) * 8);
    int sp1 = ((c1 ^ (sr & 7)) * 8);
    const unsigned short* kb0 = qk + (size_t)(b * SEQ + sr) * 2048 + 1024 + h * DKV + c0 * 8;
    const unsigned short* kb1 = kb0 + 8;
    const unsigned short* vb0 = vT + ((size_t)(b * NHEAD + h) * DKV + sr) * SEQ + c0 * 8;
    const unsigned short* vb1 = vb0 + 8;

    int rk0 = ((0 + lg) ^ (l15 & 7)) * 8;
    int rk1 = ((4 + lg) ^ (l15 & 7)) * 8;

    auto run_pass = [&](int qt) {
        int qrow = qt * 64 + w * 16 + l15;
        const unsigned short* qp = qk + (size_t)(b * SEQ + qrow) * 2048 + h * DKV + lg * 8;
        short8 qf0 = *(const short8*)qp;
        short8 qf1 = *(const short8*)(qp + 32);
        float m = -1e30f;
        f32x4 oacc[4] = {};
        f32x4 oext = {};
        int nt = qt + 1;

        short8 kr0 = *(const short8*)kb0;
        short8 kr1 = *(const short8*)kb1;
        short8 vr0 = *(const short8*)vb0;
        short8 vr1 = *(const short8*)vb1;
        *(short8*)&Ks[0][sr][sp0] = kr0;
        *(short8*)&Ks[0][sr][sp1] = kr1;
        *(short8*)&Vt[0][sr][sp0] = vr0;
        *(short8*)&Vt[0][sr][sp1] = vr1;
        if (nt > 1) {
            kr0 = *(const short8*)(kb0 + (size_t)64 * 2048);
            kr1 = *(const short8*)(kb1 + (size_t)64 * 2048);
            vr0 = *(const short8*)(vb0 + 64);
            vr1 = *(const short8*)(vb1 + 64);
        }
        __syncthreads();

        for (int t = 0; t < nt; ++t) {
            int nb = (t + 1) & 1;
            if (t + 1 < nt) {
                *(short8*)&Ks[nb][sr][sp0] = kr0;
                *(short8*)&Ks[nb][sr][sp1] = kr1;
                *(short8*)&Vt[nb][sr][sp0] = vr0;
                *(short8*)&Vt[nb][sr][sp1] = vr1;
                if (t + 2 < nt) {
                    kr0 = *(const short8*)(kb0 + (size_t)(t + 2) * 64 * 2048);
                    kr1 = *(const short8*)(kb1 + (size_t)(t + 2) * 64 * 2048);
                    vr0 = *(const short8*)(vb0 + (t + 2) * 64);
                    vr1 = *(const short8*)(vb1 + (t + 2) * 64);
                }
            }
            int bu = t & 1;

            f32x4 sc[4] = {};
            __builtin_amdgcn_s_setprio(1);
            #pragma unroll
            for (int st = 0; st < 4; ++st) {
                short8 kf0 = *(const short8*)&Ks[bu][st * 16 + l15][rk0];
                sc[st] = __builtin_amdgcn_mfma_f32_16x16x32_bf16(kf0, qf0, sc[st], 0, 0, 0);
                short8 kf1 = *(const short8*)&Ks[bu][st * 16 + l15][rk1];
                sc[st] = __builtin_amdgcn_mfma_f32_16x16x32_bf16(kf1, qf1, sc[st], 0, 0, 0);
            }
            __builtin_amdgcn_s_setprio(0);

            float pv[4][4];
            float pmax = -1e30f;
            if (t == qt) {
                int klim = qrow - t * 64;
                #pragma unroll
                for (int st = 0; st < 4; ++st) {
                    #pragma unroll
                    for (int j = 0; j < 4; ++j) {
                        float s = sc[st][j];
                        if (st * 16 + lg * 4 + j > klim) s = -1e30f;
                        pv[st][j] = s;
                        pmax = fmaxf(pmax, s);
                    }
                }
            } else {
                #pragma unroll
                for (int st = 0; st < 4; ++st) {
                    #pragma unroll
                    for (int j = 0; j < 4; ++j) {
                        pv[st][j] = sc[st][j];
                        pmax = fmaxf(pmax, sc[st][j]);
                    }
                }
            }

            if (!__all(pmax - m <= 8.0f)) {
                float pr = fmaxf(pmax, __shfl_xor(pmax, 16, 64));
                pr = fmaxf(pr, __shfl_xor(pr, 32, 64));
                float mn = fmaxf(m, pr);
                float scl2 = exp2f(m - mn);
                #pragma unroll
                for (int d = 0; d < 4; ++d)
                    #pragma unroll
                    for (int j = 0; j < 4; ++j)
                        oacc[d][j] *= scl2;
                #pragma unroll
                for (int j = 0; j < 4; ++j) oext[j] *= scl2;
                m = mn;
            }

            #pragma unroll
            for (int st = 0; st < 4; ++st) {
                float p0 = exp2f(pv[st][0] - m);
                float p1 = exp2f(pv[st][1] - m);
                float p2 = exp2f(pv[st][2] - m);
                float p3 = exp2f(pv[st][3] - m);
                unsigned int ua, ub;
                asm("v_cvt_pk_bf16_f32 %0, %1, %2" : "=v"(ua) : "v"(p0), "v"(p1));
                asm("v_cvt_pk_bf16_f32 %0, %1, %2" : "=v"(ub) : "v"(p2), "v"(p3));
                uint2 u = make_uint2(ua, ub);
                *(uint2*)&Ps[w][l15][st * 16 + lg * 4] = u;
            }

            __builtin_amdgcn_s_setprio(1);
            #pragma unroll
            for (int ks = 0; ks < 2; ++ks) {
                short8 pf = *(const short8*)&Ps[w][l15][ks * 32 + lg * 8];
                int rv = (ks == 0) ? rk0 : rk1;
                #pragma unroll
                for (int d = 0; d < 4; ++d) {
                    short8 vf = *(const short8*)&Vt[bu][d * 16 + l15][rv];
                    oacc[d] = __builtin_amdgcn_mfma_f32_16x16x32_bf16(vf, pf, oacc[d], 0, 0, 0);
                }
                oext = __builtin_amdgcn_mfma_f32_16x16x32_bf16(vf5, pf, oext, 0, 0, 0);
            }
            __builtin_amdgcn_s_setprio(0);
            __syncthreads();
        }

        float lsum = __shfl(oext[0], l15, 64);
        float inv = 1.0f / lsum;
        size_t ob = (size_t)(b * SEQ + qrow) * H_DIM + h * DKV;
        #pragma unroll
        for (int d = 0; d < 4; ++d) {
            float o0 = oacc[d][0] * inv, o1 = oacc[d][1] * inv;
            float o2 = oacc[d][2] * inv, o3 = oacc[d][3] * inv;
            unsigned int ua, ub;
            asm("v_cvt_pk_bf16_f32 %0, %1, %2" : "=v"(ua) : "v"(o0), "v"(o1));
            asm("v_cvt_pk_bf16_f32 %0, %1, %2" : "=v"(ub) : "v"(o2), "v"(o3));
            *(uint2*)&out[ob + d * 16 + lg * 4] = make_uint2(ua, ub);
        }
    };

    run_pass(31 - p);   // long half first
    run_pass(p);        // short half
}

// ---------------- launch ----------------
extern "C" void kernel_launch(void* const* d_in, const int* in_sizes, int n_in,
                              void* d_out, int out_size, void* d_ws, size_t ws_size,
                              hipStream_t stream) {
    const float* x     = (const float*)d_in[0];
    const float* ln1w  = (const float*)d_in[1];
    const float* ln1b  = (const float*)d_in[2];
    const float* Wqkv  = (const float*)d_in[3];
    const float* bqkv  = (const float*)d_in[4];
    const float* Wo    = (const float*)d_in[5];
    const float* bo    = (const float*)d_in[6];
    const float* ln2w  = (const float*)d_in[7];
    const float* ln2b  = (const float*)d_in[8];
    const float* Wfc   = (const float*)d_in[9];
    const float* bfc   = (const float*)d_in[10];
    const float* Wproj = (const float*)d_in[11];
    const float* bproj = (const float*)d_in[12];
    float* out = (float*)d_out;

    char* ws = (char*)d_ws;
    size_t off = 0;
    auto take = [&](size_t bytes) {
        void* p = ws + off;
        off += (bytes + 255) & ~(size_t)255;
        return p;
    };

    unsigned short* WqT  = (unsigned short*)take((size_t)3072 * 1024 * 2);
    unsigned short* WoT  = (unsigned short*)take((size_t)1024 * 1024 * 2);
    unsigned short* WfcT = (unsigned short*)take((size_t)4096 * 1024 * 2);
    unsigned short* WpT  = (unsigned short*)take((size_t)1024 * 4096 * 2);
    unsigned short* xn1   = (unsigned short*)take((size_t)ROWS * 1024 * 2);
    unsigned short* qk_h  = (unsigned short*)take((size_t)ROWS * 2048 * 2);
    unsigned short* vT    = (unsigned short*)take((size_t)ROWS * 1024 * 2);
    unsigned short* attn  = (unsigned short*)take((size_t)ROWS * 1024 * 2);
    unsigned short* x1h   = (unsigned short*)take((size_t)ROWS * 1024 * 2);
    unsigned short* xn2   = (unsigned short*)take((size_t)ROWS * 1024 * 2);
    unsigned short* hbuf  = (unsigned short*)take((size_t)ROWS * 4096 * 2);

    // transposes (12288 blocks) + LN1 (4096 blocks) fused into ONE launch
    prep_all<<<16384, 256, 0, stream>>>(Wqkv, Wo, Wfc, Wproj, WqT, WoT, WfcT, WpT,
                                        x, ln1w, ln1b, xn1);

    // QKV: Q (pre-scaled) | K -> qk_h, V -> vT   (grid 768; XCD chunk 8x12)
    gemmT<4, 4><<<768, 512, 0, stream>>>(xn1, WqT, bqkv, nullptr, nullptr, qk_h, vT, 8, 12, 2, 3072, 1024);

    // causal attention -> attn (bf16), paired q-tiles, grid 512 x 256 thr
    attn_mfma<<<512, 256, 0, stream>>>(qk_h, vT, attn);

    // x1h = bf16(x + attn @ Wo + bo)
    gemmT<5, 2><<<512, 512, 0, stream>>>(attn, WoT, bo, x, nullptr, x1h, nullptr, 4, 16, 1, 1024, 1024);

    // LN2 (bf16 in) -> xn2
    ln_bf16in<<<ROWS, 256, 0, stream>>>(x1h, ln2w, ln2b, xn2);

    // h = gelu(xn2 @ Wfc + bfc)   (grid 1024; XCD chunk 8x16)
    gemmT<2, 4><<<1024, 512, 0, stream>>>(xn2, WfcT, bfc, nullptr, nullptr, hbuf, nullptr, 8, 16, 2, 4096, 1024);

    // out = x1h + h @ Wproj + bproj
    gemmT<6, 2><<<512, 512, 0, stream>>>(hbuf, WpT, bproj, nullptr, out, nullptr, x1h, 4, 16, 1, 1024, 4096);
}